// Round 13
// baseline (379.108 us; speedup 1.0000x reference)
//
#include <hip/hip_runtime.h>

#define D_MODEL 768
#define NHEADS 12
#define DEPTH 64
#define SEQ 2048
#define NROWS 4096   // B*S

typedef float f32x4 __attribute__((ext_vector_type(4)));
typedef short bf16x8 __attribute__((ext_vector_type(8)));
typedef unsigned u32x2 __attribute__((ext_vector_type(2)));
typedef unsigned u32x4 __attribute__((ext_vector_type(4)));

#define MFMA16(a, b, c) __builtin_amdgcn_mfma_f32_16x16x32_bf16((a), (b), (c), 0, 0, 0)

__device__ __forceinline__ short f2bf(float f) {
    union { float f; unsigned u; } v; v.f = f;
    unsigned r = (v.u + 0x7FFFu + ((v.u >> 16) & 1u)) >> 16;
    return (short)r;
}
__device__ __forceinline__ unsigned cvtpk(float a, float b) {
    unsigned r;
    asm("v_cvt_pk_bf16_f32 %0, %1, %2" : "=v"(r) : "v"(a), "v"(b));
    return r;
}

struct KF { bf16x8 a0, a1, b0, b1; };          // 16 VGPR
struct VF { short4 x[8]; };                     // 16 VGPR

__device__ __forceinline__ KF loadK(const short* __restrict__ Kp, int k0, int r, int h) {
    KF f;
    const short* kr0 = Kp + (k0 + r) * DEPTH + 8 * h;
    const short* kr1 = kr0 + 16 * DEPTH;
    f.a0 = *(const bf16x8*)(kr0);
    f.a1 = *(const bf16x8*)(kr0 + 32);
    f.b0 = *(const bf16x8*)(kr1);
    f.b1 = *(const bf16x8*)(kr1 + 32);
    return f;
}
// vt blocked layout: [bh][s>>5][d][32]
__device__ __forceinline__ VF loadV(const short* __restrict__ Vb, int k0, int r, int h) {
    VF f;
    const short* blk = Vb + (k0 >> 5) * (DEPTH * 32) + 4 * h;
#pragma unroll
    for (int nt = 0; nt < 4; nt++) {
        const short* row = blk + (16 * nt + r) * 32;
        f.x[2 * nt]     = *(const short4*)(row);
        f.x[2 * nt + 1] = *(const short4*)(row + 16);
    }
    return f;
}

// ---------------------------------------------------------------------------
// Kernel X: cast q,k,v fp32 -> bf16 once.
// ---------------------------------------------------------------------------
__global__ __launch_bounds__(256) void xcast_kernel(
    const float* __restrict__ q, const float* __restrict__ k, const float* __restrict__ v,
    short* __restrict__ xb)
{
    int z = blockIdx.y;
    const float* src = (z == 0) ? q : (z == 1) ? k : v;
    short* dst = xb + (size_t)z * NROWS * D_MODEL;
    int i = (blockIdx.x * 256 + threadIdx.x) * 8;
    float4 f0 = *(const float4*)(src + i);
    float4 f1 = *(const float4*)(src + i + 4);
    u32x4 o;
    o[0] = cvtpk(f0.x, f0.y); o[1] = cvtpk(f0.z, f0.w);
    o[2] = cvtpk(f1.x, f1.y); o[3] = cvtpk(f1.z, f1.w);
    *(u32x4*)(dst + i) = o;
}

// ---------------------------------------------------------------------------
// Kernel W: transpose + convert the four weight matrices to bf16.
// ---------------------------------------------------------------------------
__global__ __launch_bounds__(256) void wtrans_kernel(
    const float* __restrict__ wq, const float* __restrict__ wk,
    const float* __restrict__ wv, const float* __restrict__ wo,
    short* __restrict__ wt)
{
    __shared__ float tile[32][33];
    int wi = blockIdx.z;
    const float* W = (wi == 0) ? wq : (wi == 1) ? wk : (wi == 2) ? wv : wo;
    short* out = wt + wi * D_MODEL * D_MODEL;
    int k0 = blockIdx.x * 32, n0 = blockIdx.y * 32;
    int t = threadIdx.x;
    int tx = t & 31, ty = t >> 5;
#pragma unroll
    for (int i = 0; i < 4; i++) {
        int kk = ty + i * 8;
        tile[kk][tx] = W[(k0 + kk) * D_MODEL + n0 + tx];
    }
    __syncthreads();
#pragma unroll
    for (int i = 0; i < 4; i++) {
        int nn = ty + i * 8;
        out[(n0 + nn) * D_MODEL + k0 + tx] = f2bf(tile[tx][nn]);
    }
}

// ---------------------------------------------------------------------------
// Kernel A: fused QKV projection GEMM; 128-row x 64-col blocks (8 waves,
// B panel amortized 2x), register double-buffered.
// z=0: Q (pre-scaled), z=1: K (swapped-operand, 8B stores);
// z=2: V (k-blocked transposed vt[bh][s>>5][d][s&31]).
// ---------------------------------------------------------------------------
__global__ __launch_bounds__(512) void qkv_gemm(
    const short* __restrict__ xb, const short* __restrict__ wt,
    const float* __restrict__ bq, const float* __restrict__ bk, const float* __restrict__ bv,
    short* __restrict__ qh, short* __restrict__ kh, short* __restrict__ vt)
{
    int z = blockIdx.z;
    const short* A  = xb + (size_t)z * NROWS * D_MODEL;
    const short* Bw = wt + z * D_MODEL * D_MODEL;

    int m0 = blockIdx.x * 128, n0 = blockIdx.y * 64;
    int lane = threadIdx.x & 63, w = threadIdx.x >> 6;   // w in 0..7
    int r = lane & 15, h = lane >> 4;
    const short* arow = A + (m0 + 16 * w + r) * D_MODEL;

    f32x4 acc[4] = {};
    bf16x8 ac = *(const bf16x8*)(arow + 8 * h);
    bf16x8 bc[4];
#pragma unroll
    for (int nt = 0; nt < 4; nt++)
        bc[nt] = *(const bf16x8*)(Bw + (n0 + 16 * nt + r) * D_MODEL + 8 * h);

    if (z == 2) {
        for (int k0 = 0; k0 < D_MODEL; k0 += 32) {
            int kn = (k0 + 32 < D_MODEL) ? (k0 + 32) : 0;
            bf16x8 an = *(const bf16x8*)(arow + kn + 8 * h);
            bf16x8 bn[4];
#pragma unroll
            for (int nt = 0; nt < 4; nt++)
                bn[nt] = *(const bf16x8*)(Bw + (n0 + 16 * nt + r) * D_MODEL + kn + 8 * h);
#pragma unroll
            for (int nt = 0; nt < 4; nt++)
                acc[nt] = MFMA16(ac, bc[nt], acc[nt]);   // rows=s, cols=d
            ac = an;
#pragma unroll
            for (int nt = 0; nt < 4; nt++) bc[nt] = bn[nt];
        }
#pragma unroll
        for (int nt = 0; nt < 4; nt++) {
            int col = n0 + 16 * nt + r;
            float bsv = bv[col];
            int hh = col >> 6, dd = col & 63;
            int m = m0 + 16 * w + 4 * h;
            int b = m >> 11, s = m & 2047;
            short4 pk;
            pk.x = f2bf(acc[nt][0] + bsv);
            pk.y = f2bf(acc[nt][1] + bsv);
            pk.z = f2bf(acc[nt][2] + bsv);
            pk.w = f2bf(acc[nt][3] + bsv);
            long off = (((long)(b * NHEADS + hh) * 64 + (s >> 5)) * DEPTH + dd) * 32 + (s & 31);
            *(short4*)(vt + off) = pk;
        }
    } else {
        const float* bias = (z == 0) ? bq : bk;
        float scl = (z == 0) ? 0.18033688011112042f : 1.0f;  // 0.125*log2(e)
        short* dst = (z == 0) ? qh : kh;
        for (int k0 = 0; k0 < D_MODEL; k0 += 32) {
            int kn = (k0 + 32 < D_MODEL) ? (k0 + 32) : 0;
            bf16x8 an = *(const bf16x8*)(arow + kn + 8 * h);
            bf16x8 bn[4];
#pragma unroll
            for (int nt = 0; nt < 4; nt++)
                bn[nt] = *(const bf16x8*)(Bw + (n0 + 16 * nt + r) * D_MODEL + kn + 8 * h);
#pragma unroll
            for (int nt = 0; nt < 4; nt++)
                acc[nt] = MFMA16(bc[nt], ac, acc[nt]);   // SWAPPED: rows=d, cols=s
            ac = an;
#pragma unroll
            for (int nt = 0; nt < 4; nt++) bc[nt] = bn[nt];
        }
        int hh = n0 >> 6;
        int m = m0 + 16 * w + r;
        int b = m >> 11, s = m & 2047;
        long rowoff = ((long)(b * NHEADS + hh) * SEQ + s) * DEPTH;
#pragma unroll
        for (int nt = 0; nt < 4; nt++) {
            int dd = 16 * nt + 4 * h;
            float4 b4 = *(const float4*)(bias + n0 + dd);
            float v0 = (acc[nt][0] + b4.x) * scl;
            float v1 = (acc[nt][1] + b4.y) * scl;
            float v2 = (acc[nt][2] + b4.z) * scl;
            float v3 = (acc[nt][3] + b4.w) * scl;
            u32x2 pk = {cvtpk(v0, v1), cvtpk(v2, v3)};
            *(u32x2*)&dst[rowoff + dd] = pk;
        }
    }
}

// ---------------------------------------------------------------------------
// Kernel B: attention v8 — r12 merged structure + pass-2 register prefetch.
// Block = 64 q-rows, 8 waves = 2 q-groups(32 rows) x 4 col-subchunks.
// Grid 768, XCD-pinned. Pass 1: K-only quarter sums (dbuf). Pass 2: per
// 256-col chunk {2 steps, each with next-step K/V prefetched one full step
// ahead} -> barrier -> pure NT store phase -> barrier. O merged via plds.
// ---------------------------------------------------------------------------
__global__ __launch_bounds__(512, 2) void attn_kernel(
    const short* __restrict__ qh, const short* __restrict__ kh, const short* __restrict__ vt,
    float* __restrict__ attn, short* __restrict__ ctx)
{
    __shared__ float plds[64 * 256];          // 64 KB P-chunk / O-merge buffer
    __shared__ float sml[2][4][2][16];

    int wgid = blockIdx.x;
    int xcd = wgid & 7;
    int idx = wgid >> 3;             // 0..95
    int bh = xcd * 3 + (idx >> 5);   // 3 heads per XCD
    int q0 = (idx & 31) * 64;

    int lane = threadIdx.x & 63, w = threadIdx.x >> 6;
    int wq2 = w >> 2, kc = w & 3;    // q-group (32 rows), col-subchunk (64)
    int r = lane & 15, h = lane >> 4;
    int qbase = q0 + 32 * wq2;

    const short* Qp = qh + ((long)bh * SEQ + qbase) * DEPTH;
    const short* Kp = kh + (long)bh * SEQ * DEPTH;
    const short* Vb = vt + (long)bh * (64 * DEPTH * 32);

    bf16x8 qf[2][2];
#pragma unroll
    for (int j = 0; j < 2; j++) {
        qf[j][0] = *(const bf16x8*)(Qp + (16 * j + r) * DEPTH + 8 * h);
        qf[j][1] = *(const bf16x8*)(Qp + (16 * j + r) * DEPTH + 32 + 8 * h);
    }

    // ---- pass 1: K-only sums over this wave's k-quarter (dbuf) ----
    float l0 = 0.f, l1 = 0.f;
    {
        int kstart = kc * 512, kend = kstart + 512;
        KF kcur = loadK(Kp, kstart, r, h);
        for (int k0 = kstart; k0 < kend; k0 += 32) {
            int kn = (k0 + 32 < kend) ? (k0 + 32) : kstart;
            KF knxt = loadK(Kp, kn, r, h);
#pragma unroll
            for (int j = 0; j < 2; j++) {
                f32x4 s0 = {}, s1 = {};
                s0 = MFMA16(kcur.a0, qf[j][0], s0);
                s1 = MFMA16(kcur.b0, qf[j][0], s1);
                s0 = MFMA16(kcur.a1, qf[j][1], s0);
                s1 = MFMA16(kcur.b1, qf[j][1], s1);
                float sum = exp2f(s0[0]) + exp2f(s0[1]) + exp2f(s0[2]) + exp2f(s0[3])
                          + exp2f(s1[0]) + exp2f(s1[1]) + exp2f(s1[2]) + exp2f(s1[3]);
                if (j == 0) l0 += sum; else l1 += sum;
            }
            kcur = knxt;
        }
    }
    l0 += __shfl_xor(l0, 16); l0 += __shfl_xor(l0, 32);
    l1 += __shfl_xor(l1, 16); l1 += __shfl_xor(l1, 32);
    if (lane < 16) {
        sml[wq2][kc][0][lane] = l0;
        sml[wq2][kc][1][lane] = l1;
    }
    __syncthreads();
    float rl[2];
#pragma unroll
    for (int j = 0; j < 2; j++)
        rl[j] = 1.0f / (sml[wq2][0][j][r] + sml[wq2][1][j][r] +
                        sml[wq2][2][j][r] + sml[wq2][3][j][r]);

    // ---- pass 2: prefetched chunked compute -> LDS -> phased NT stores ----
    f32x4 o[2][4] = {};
    int rsw = r & 7;

    // flat step n in 0..15: k0(n) = (n>>1)*256 + kc*64 + (n&1)*32
    KF kf = loadK(Kp, kc * 64, r, h);
    VF vf = loadV(Vb, kc * 64, r, h);

    for (int chunk = 0; chunk < 8; chunk++) {
#pragma unroll
        for (int it = 0; it < 2; it++) {
            int n = chunk * 2 + it;
            int nn = (n + 1) & 15;                      // last prefetch wraps (dummy)
            int knext = (nn >> 1) * 256 + kc * 64 + (nn & 1) * 32;
            KF kpre = loadK(Kp, knext, r, h);
            VF vpre = loadV(Vb, knext, r, h);

#pragma unroll
            for (int j = 0; j < 2; j++) {
                f32x4 s0 = {}, s1 = {};
                s0 = MFMA16(kf.a0, qf[j][0], s0);
                s1 = MFMA16(kf.b0, qf[j][0], s1);
                s0 = MFMA16(kf.a1, qf[j][1], s0);
                s1 = MFMA16(kf.b1, qf[j][1], s1);

                float p0 = exp2f(s0[0]) * rl[j], p1 = exp2f(s0[1]) * rl[j];
                float p2 = exp2f(s0[2]) * rl[j], p3 = exp2f(s0[3]) * rl[j];
                float p4 = exp2f(s1[0]) * rl[j], p5 = exp2f(s1[1]) * rl[j];
                float p6 = exp2f(s1[2]) * rl[j], p7 = exp2f(s1[3]) * rl[j];

                int row = wq2 * 32 + 16 * j + r;
                int G0 = kc * 16 + it * 8 + h;
                int G1 = G0 + 4;
                int pg0 = (G0 & ~7) | ((G0 & 7) ^ rsw);
                int pg1 = (G1 & ~7) | ((G1 & 7) ^ rsw);
                f32x4 v0 = {p0, p1, p2, p3};
                f32x4 v1 = {p4, p5, p6, p7};
                *(f32x4*)&plds[row * 256 + pg0 * 4] = v0;
                *(f32x4*)&plds[row * 256 + pg1 * 4] = v1;

                union { unsigned u[4]; bf16x8 v; } pa;
                pa.u[0] = cvtpk(p0, p1); pa.u[1] = cvtpk(p2, p3);
                pa.u[2] = cvtpk(p4, p5); pa.u[3] = cvtpk(p6, p7);
#pragma unroll
                for (int nt = 0; nt < 4; nt++) {
                    union { short4 s4[2]; bf16x8 v; } vv;
                    vv.s4[0] = vf.x[2 * nt];
                    vv.s4[1] = vf.x[2 * nt + 1];
                    o[j][nt] = MFMA16(vv.v, pa.v, o[j][nt]);
                }
            }
            kf = kpre;
            vf = vpre;
        }
        __syncthreads();

        // store phase: wave w owns rows 8w..8w+7; 1KB contiguous per instr
#pragma unroll
        for (int rr = 0; rr < 8; rr++) {
            int R = w * 8 + rr;
            float* arow = attn + ((long)(bh * SEQ + q0 + R)) * SEQ + chunk * 256;
            int pg = (lane & ~7) | ((lane & 7) ^ (R & 7));
            f32x4 val = *(const f32x4*)&plds[R * 256 + pg * 4];
            __builtin_nontemporal_store(val, (f32x4*)(arow + lane * 4));
        }
        __syncthreads();
    }

    // ---- O merge across the 4 col-subchunk waves (reuse plds) ----
    if (kc != 0) {
#pragma unroll
        for (int j = 0; j < 2; j++)
#pragma unroll
            for (int nt = 0; nt < 4; nt++)
                *(f32x4*)&plds[((((wq2 * 3 + (kc - 1)) * 2 + j) * 4 + nt) * 64 + lane) * 4] =
                    o[j][nt];
    }
    __syncthreads();
    if (kc == 0) {
        int b = bh / NHEADS, head = bh % NHEADS;
#pragma unroll
        for (int j = 0; j < 2; j++) {
            long crow = ((long)(b * SEQ + qbase + 16 * j + r)) * D_MODEL + head * DEPTH;
#pragma unroll
            for (int nt = 0; nt < 4; nt++) {
                f32x4 acc = o[j][nt];
#pragma unroll
                for (int m = 0; m < 3; m++) {
                    f32x4 op = *(const f32x4*)
                        &plds[((((wq2 * 3 + m) * 2 + j) * 4 + nt) * 64 + lane) * 4];
                    acc[0] += op[0]; acc[1] += op[1];
                    acc[2] += op[2]; acc[3] += op[3];
                }
                *(unsigned*)&ctx[crow + 16 * nt + 4 * h]     = cvtpk(acc[0], acc[1]);
                *(unsigned*)&ctx[crow + 16 * nt + 4 * h + 2] = cvtpk(acc[2], acc[3]);
            }
        }
    }
}

// ---------------------------------------------------------------------------
// Kernel C: output projection; 128-row blocks (8 waves), dbuf, float4 stores.
// ---------------------------------------------------------------------------
__global__ __launch_bounds__(512) void out_gemm(
    const short* __restrict__ ctx, const short* __restrict__ wt3,
    const float* __restrict__ bo, float* __restrict__ out)
{
    int m0 = blockIdx.x * 128, n0 = blockIdx.y * 64;
    int lane = threadIdx.x & 63, w = threadIdx.x >> 6;   // w in 0..7
    int r = lane & 15, h = lane >> 4;

    f32x4 acc[4] = {};
    const short* arow = ctx + (m0 + 16 * w + r) * D_MODEL;

    bf16x8 ac = *(const bf16x8*)(arow + 8 * h);
    bf16x8 bc[4];
#pragma unroll
    for (int nt = 0; nt < 4; nt++)
        bc[nt] = *(const bf16x8*)(wt3 + (n0 + 16 * nt + r) * D_MODEL + 8 * h);

    for (int k0 = 0; k0 < D_MODEL; k0 += 32) {
        int kn = (k0 + 32 < D_MODEL) ? (k0 + 32) : 0;
        bf16x8 an = *(const bf16x8*)(arow + kn + 8 * h);
        bf16x8 bn[4];
#pragma unroll
        for (int nt = 0; nt < 4; nt++)
            bn[nt] = *(const bf16x8*)(wt3 + (n0 + 16 * nt + r) * D_MODEL + kn + 8 * h);
#pragma unroll
        for (int nt = 0; nt < 4; nt++)
            acc[nt] = MFMA16(bc[nt], ac, acc[nt]);   // SWAPPED: rows=n, cols=m
        ac = an;
#pragma unroll
        for (int nt = 0; nt < 4; nt++) bc[nt] = bn[nt];
    }
    int m = m0 + 16 * w + r;
#pragma unroll
    for (int nt = 0; nt < 4; nt++) {
        int n = n0 + 16 * nt + 4 * h;
        float4 b4 = *(const float4*)(bo + n);
        f32x4 res = {acc[nt][0] + b4.x, acc[nt][1] + b4.y,
                     acc[nt][2] + b4.z, acc[nt][3] + b4.w};
        *(f32x4*)(out + (long)m * D_MODEL + n) = res;
    }
}

// ---------------------------------------------------------------------------
extern "C" void kernel_launch(void* const* d_in, const int* in_sizes, int n_in,
                              void* d_out, int out_size, void* d_ws, size_t ws_size,
                              hipStream_t stream)
{
    const float* v  = (const float*)d_in[0];
    const float* k  = (const float*)d_in[1];
    const float* q  = (const float*)d_in[2];
    const float* wq = (const float*)d_in[3];
    const float* bq = (const float*)d_in[4];
    const float* wk = (const float*)d_in[5];
    const float* bk = (const float*)d_in[6];
    const float* wv = (const float*)d_in[7];
    const float* bv = (const float*)d_in[8];
    const float* wo = (const float*)d_in[9];
    const float* bo = (const float*)d_in[10];

    char* ws = (char*)d_ws;
    const size_t WT_BYTES  = (size_t)4 * D_MODEL * D_MODEL * 2;    // 4.7 MB
    const size_t XB_BYTES  = (size_t)3 * NROWS * D_MODEL * 2;      // 18.9 MB
    const size_t HB_BYTES  = (size_t)2 * NHEADS * SEQ * DEPTH * 2; // 6.3 MB
    short* wt  = (short*)(ws);
    short* xb  = (short*)(ws + WT_BYTES);
    short* qh  = (short*)(ws + WT_BYTES + XB_BYTES);
    short* kh  = (short*)(ws + WT_BYTES + XB_BYTES + HB_BYTES);
    short* vt  = (short*)(ws + WT_BYTES + XB_BYTES + 2 * HB_BYTES);
    short* ctx = (short*)(ws + WT_BYTES + XB_BYTES + 3 * HB_BYTES);

    float* out  = (float*)d_out;
    float* attn = (float*)d_out + (size_t)NROWS * D_MODEL;

    xcast_kernel<<<dim3(1536, 3), dim3(256), 0, stream>>>(q, k, v, xb);
    wtrans_kernel<<<dim3(24, 24, 4), dim3(256), 0, stream>>>(wq, wk, wv, wo, wt);
    qkv_gemm<<<dim3(32, 12, 3), dim3(512), 0, stream>>>(xb, wt, bq, bk, bv, qh, kh, vt);
    attn_kernel<<<dim3(768), dim3(512), 0, stream>>>(qh, kh, vt, attn, ctx);
    out_gemm<<<dim3(32, 12), dim3(512), 0, stream>>>(ctx, wt + 3 * D_MODEL * D_MODEL, bo, out);
}

// Round 14
// 367.248 us; speedup vs baseline: 1.0323x; 1.0323x over previous
//
#include <hip/hip_runtime.h>

#define D_MODEL 768
#define NHEADS 12
#define DEPTH 64
#define SEQ 2048
#define NROWS 4096   // B*S

typedef float f32x4 __attribute__((ext_vector_type(4)));
typedef short bf16x8 __attribute__((ext_vector_type(8)));
typedef unsigned u32x2 __attribute__((ext_vector_type(2)));
typedef unsigned u32x4 __attribute__((ext_vector_type(4)));

#define MFMA16(a, b, c) __builtin_amdgcn_mfma_f32_16x16x32_bf16((a), (b), (c), 0, 0, 0)

__device__ __forceinline__ short f2bf(float f) {
    union { float f; unsigned u; } v; v.f = f;
    unsigned r = (v.u + 0x7FFFu + ((v.u >> 16) & 1u)) >> 16;
    return (short)r;
}
__device__ __forceinline__ unsigned cvtpk(float a, float b) {
    unsigned r;
    asm("v_cvt_pk_bf16_f32 %0, %1, %2" : "=v"(r) : "v"(a), "v"(b));
    return r;
}

struct KF { bf16x8 a0, a1, b0, b1; };          // 16 VGPR
struct VF { short4 x[8]; };                     // 16 VGPR

__device__ __forceinline__ KF loadK(const short* __restrict__ Kp, int k0, int r, int h) {
    KF f;
    const short* kr0 = Kp + (k0 + r) * DEPTH + 8 * h;
    const short* kr1 = kr0 + 16 * DEPTH;
    f.a0 = *(const bf16x8*)(kr0);
    f.a1 = *(const bf16x8*)(kr0 + 32);
    f.b0 = *(const bf16x8*)(kr1);
    f.b1 = *(const bf16x8*)(kr1 + 32);
    return f;
}
// vt blocked layout: [bh][s>>5][d][32]
__device__ __forceinline__ VF loadV(const short* __restrict__ Vb, int k0, int r, int h) {
    VF f;
    const short* blk = Vb + (k0 >> 5) * (DEPTH * 32) + 4 * h;
#pragma unroll
    for (int nt = 0; nt < 4; nt++) {
        const short* row = blk + (16 * nt + r) * 32;
        f.x[2 * nt]     = *(const short4*)(row);
        f.x[2 * nt + 1] = *(const short4*)(row + 16);
    }
    return f;
}

// ---------------------------------------------------------------------------
// Kernel X: cast q,k,v fp32 -> bf16 once.
// ---------------------------------------------------------------------------
__global__ __launch_bounds__(256) void xcast_kernel(
    const float* __restrict__ q, const float* __restrict__ k, const float* __restrict__ v,
    short* __restrict__ xb)
{
    int z = blockIdx.y;
    const float* src = (z == 0) ? q : (z == 1) ? k : v;
    short* dst = xb + (size_t)z * NROWS * D_MODEL;
    int i = (blockIdx.x * 256 + threadIdx.x) * 8;
    float4 f0 = *(const float4*)(src + i);
    float4 f1 = *(const float4*)(src + i + 4);
    u32x4 o;
    o[0] = cvtpk(f0.x, f0.y); o[1] = cvtpk(f0.z, f0.w);
    o[2] = cvtpk(f1.x, f1.y); o[3] = cvtpk(f1.z, f1.w);
    *(u32x4*)(dst + i) = o;
}

// ---------------------------------------------------------------------------
// Kernel W: transpose + convert the four weight matrices to bf16.
// ---------------------------------------------------------------------------
__global__ __launch_bounds__(256) void wtrans_kernel(
    const float* __restrict__ wq, const float* __restrict__ wk,
    const float* __restrict__ wv, const float* __restrict__ wo,
    short* __restrict__ wt)
{
    __shared__ float tile[32][33];
    int wi = blockIdx.z;
    const float* W = (wi == 0) ? wq : (wi == 1) ? wk : (wi == 2) ? wv : wo;
    short* out = wt + wi * D_MODEL * D_MODEL;
    int k0 = blockIdx.x * 32, n0 = blockIdx.y * 32;
    int t = threadIdx.x;
    int tx = t & 31, ty = t >> 5;
#pragma unroll
    for (int i = 0; i < 4; i++) {
        int kk = ty + i * 8;
        tile[kk][tx] = W[(k0 + kk) * D_MODEL + n0 + tx];
    }
    __syncthreads();
#pragma unroll
    for (int i = 0; i < 4; i++) {
        int nn = ty + i * 8;
        out[(n0 + nn) * D_MODEL + k0 + tx] = f2bf(tile[tx][nn]);
    }
}

// ---------------------------------------------------------------------------
// Kernel A: fused QKV projection GEMM; 128-row x 64-col blocks (8 waves),
// register double-buffered.
// z=0: Q (pre-scaled), z=1: K (swapped-operand, 8B stores);
// z=2: V (k-blocked transposed vt[bh][s>>5][d][s&31]).
// ---------------------------------------------------------------------------
__global__ __launch_bounds__(512) void qkv_gemm(
    const short* __restrict__ xb, const short* __restrict__ wt,
    const float* __restrict__ bq, const float* __restrict__ bk, const float* __restrict__ bv,
    short* __restrict__ qh, short* __restrict__ kh, short* __restrict__ vt)
{
    int z = blockIdx.z;
    const short* A  = xb + (size_t)z * NROWS * D_MODEL;
    const short* Bw = wt + z * D_MODEL * D_MODEL;

    int m0 = blockIdx.x * 128, n0 = blockIdx.y * 64;
    int lane = threadIdx.x & 63, w = threadIdx.x >> 6;   // w in 0..7
    int r = lane & 15, h = lane >> 4;
    const short* arow = A + (m0 + 16 * w + r) * D_MODEL;

    f32x4 acc[4] = {};
    bf16x8 ac = *(const bf16x8*)(arow + 8 * h);
    bf16x8 bc[4];
#pragma unroll
    for (int nt = 0; nt < 4; nt++)
        bc[nt] = *(const bf16x8*)(Bw + (n0 + 16 * nt + r) * D_MODEL + 8 * h);

    if (z == 2) {
        for (int k0 = 0; k0 < D_MODEL; k0 += 32) {
            int kn = (k0 + 32 < D_MODEL) ? (k0 + 32) : 0;
            bf16x8 an = *(const bf16x8*)(arow + kn + 8 * h);
            bf16x8 bn[4];
#pragma unroll
            for (int nt = 0; nt < 4; nt++)
                bn[nt] = *(const bf16x8*)(Bw + (n0 + 16 * nt + r) * D_MODEL + kn + 8 * h);
#pragma unroll
            for (int nt = 0; nt < 4; nt++)
                acc[nt] = MFMA16(ac, bc[nt], acc[nt]);   // rows=s, cols=d
            ac = an;
#pragma unroll
            for (int nt = 0; nt < 4; nt++) bc[nt] = bn[nt];
        }
#pragma unroll
        for (int nt = 0; nt < 4; nt++) {
            int col = n0 + 16 * nt + r;
            float bsv = bv[col];
            int hh = col >> 6, dd = col & 63;
            int m = m0 + 16 * w + 4 * h;
            int b = m >> 11, s = m & 2047;
            short4 pk;
            pk.x = f2bf(acc[nt][0] + bsv);
            pk.y = f2bf(acc[nt][1] + bsv);
            pk.z = f2bf(acc[nt][2] + bsv);
            pk.w = f2bf(acc[nt][3] + bsv);
            long off = (((long)(b * NHEADS + hh) * 64 + (s >> 5)) * DEPTH + dd) * 32 + (s & 31);
            *(short4*)(vt + off) = pk;
        }
    } else {
        const float* bias = (z == 0) ? bq : bk;
        float scl = (z == 0) ? 0.18033688011112042f : 1.0f;  // 0.125*log2(e)
        short* dst = (z == 0) ? qh : kh;
        for (int k0 = 0; k0 < D_MODEL; k0 += 32) {
            int kn = (k0 + 32 < D_MODEL) ? (k0 + 32) : 0;
            bf16x8 an = *(const bf16x8*)(arow + kn + 8 * h);
            bf16x8 bn[4];
#pragma unroll
            for (int nt = 0; nt < 4; nt++)
                bn[nt] = *(const bf16x8*)(Bw + (n0 + 16 * nt + r) * D_MODEL + kn + 8 * h);
#pragma unroll
            for (int nt = 0; nt < 4; nt++)
                acc[nt] = MFMA16(bc[nt], ac, acc[nt]);   // SWAPPED: rows=d, cols=s
            ac = an;
#pragma unroll
            for (int nt = 0; nt < 4; nt++) bc[nt] = bn[nt];
        }
        int hh = n0 >> 6;
        int m = m0 + 16 * w + r;
        int b = m >> 11, s = m & 2047;
        long rowoff = ((long)(b * NHEADS + hh) * SEQ + s) * DEPTH;
#pragma unroll
        for (int nt = 0; nt < 4; nt++) {
            int dd = 16 * nt + 4 * h;
            float4 b4 = *(const float4*)(bias + n0 + dd);
            float v0 = (acc[nt][0] + b4.x) * scl;
            float v1 = (acc[nt][1] + b4.y) * scl;
            float v2 = (acc[nt][2] + b4.z) * scl;
            float v3 = (acc[nt][3] + b4.w) * scl;
            u32x2 pk = {cvtpk(v0, v1), cvtpk(v2, v3)};
            *(u32x2*)&dst[rowoff + dd] = pk;
        }
    }
}

// ---------------------------------------------------------------------------
// Kernel B: attention v7 — EXACT r12 structure (proven 340 µs). QK once,
// phased NT stores, PV fused, no pass-2 prefetch, __launch_bounds__(512,4).
// ---------------------------------------------------------------------------
__global__ __launch_bounds__(512, 4) void attn_kernel(
    const short* __restrict__ qh, const short* __restrict__ kh, const short* __restrict__ vt,
    float* __restrict__ attn, short* __restrict__ ctx)
{
    __shared__ float plds[64 * 256];          // 64 KB P-chunk / O-merge buffer
    __shared__ float sml[2][4][2][16];

    int wgid = blockIdx.x;
    int xcd = wgid & 7;
    int idx = wgid >> 3;             // 0..95
    int bh = xcd * 3 + (idx >> 5);   // 3 heads per XCD
    int q0 = (idx & 31) * 64;

    int lane = threadIdx.x & 63, w = threadIdx.x >> 6;
    int wq2 = w >> 2, kc = w & 3;    // q-group (32 rows), col-subchunk (64)
    int r = lane & 15, h = lane >> 4;
    int qbase = q0 + 32 * wq2;

    const short* Qp = qh + ((long)bh * SEQ + qbase) * DEPTH;
    const short* Kp = kh + (long)bh * SEQ * DEPTH;
    const short* Vb = vt + (long)bh * (64 * DEPTH * 32);

    bf16x8 qf[2][2];
#pragma unroll
    for (int j = 0; j < 2; j++) {
        qf[j][0] = *(const bf16x8*)(Qp + (16 * j + r) * DEPTH + 8 * h);
        qf[j][1] = *(const bf16x8*)(Qp + (16 * j + r) * DEPTH + 32 + 8 * h);
    }

    // ---- pass 1: K-only sums over this wave's k-quarter ----
    float l0 = 0.f, l1 = 0.f;
    {
        int kstart = kc * 512, kend = kstart + 512;
        KF kcur = loadK(Kp, kstart, r, h);
        for (int k0 = kstart; k0 < kend; k0 += 32) {
            int kn = (k0 + 32 < kend) ? (k0 + 32) : kstart;
            KF knxt = loadK(Kp, kn, r, h);
#pragma unroll
            for (int j = 0; j < 2; j++) {
                f32x4 s0 = {}, s1 = {};
                s0 = MFMA16(kcur.a0, qf[j][0], s0);
                s1 = MFMA16(kcur.b0, qf[j][0], s1);
                s0 = MFMA16(kcur.a1, qf[j][1], s0);
                s1 = MFMA16(kcur.b1, qf[j][1], s1);
                float sum = exp2f(s0[0]) + exp2f(s0[1]) + exp2f(s0[2]) + exp2f(s0[3])
                          + exp2f(s1[0]) + exp2f(s1[1]) + exp2f(s1[2]) + exp2f(s1[3]);
                if (j == 0) l0 += sum; else l1 += sum;
            }
            kcur = knxt;
        }
    }
    l0 += __shfl_xor(l0, 16); l0 += __shfl_xor(l0, 32);
    l1 += __shfl_xor(l1, 16); l1 += __shfl_xor(l1, 32);
    if (lane < 16) {
        sml[wq2][kc][0][lane] = l0;
        sml[wq2][kc][1][lane] = l1;
    }
    __syncthreads();
    float rl[2];
#pragma unroll
    for (int j = 0; j < 2; j++)
        rl[j] = 1.0f / (sml[wq2][0][j][r] + sml[wq2][1][j][r] +
                        sml[wq2][2][j][r] + sml[wq2][3][j][r]);

    // ---- pass 2: chunked compute -> LDS -> phased NT stores; PV fused ----
    f32x4 o[2][4] = {};
    int rsw = r & 7;

    for (int chunk = 0; chunk < 8; chunk++) {
#pragma unroll
        for (int it = 0; it < 2; it++) {
            int k0 = chunk * 256 + kc * 64 + it * 32;
            KF kf = loadK(Kp, k0, r, h);
            VF vf = loadV(Vb, k0, r, h);
#pragma unroll
            for (int j = 0; j < 2; j++) {
                f32x4 s0 = {}, s1 = {};
                s0 = MFMA16(kf.a0, qf[j][0], s0);
                s1 = MFMA16(kf.b0, qf[j][0], s1);
                s0 = MFMA16(kf.a1, qf[j][1], s0);
                s1 = MFMA16(kf.b1, qf[j][1], s1);

                float p0 = exp2f(s0[0]) * rl[j], p1 = exp2f(s0[1]) * rl[j];
                float p2 = exp2f(s0[2]) * rl[j], p3 = exp2f(s0[3]) * rl[j];
                float p4 = exp2f(s1[0]) * rl[j], p5 = exp2f(s1[1]) * rl[j];
                float p6 = exp2f(s1[2]) * rl[j], p7 = exp2f(s1[3]) * rl[j];

                int row = wq2 * 32 + 16 * j + r;
                int G0 = kc * 16 + it * 8 + h;
                int G1 = G0 + 4;
                int pg0 = (G0 & ~7) | ((G0 & 7) ^ rsw);
                int pg1 = (G1 & ~7) | ((G1 & 7) ^ rsw);
                f32x4 v0 = {p0, p1, p2, p3};
                f32x4 v1 = {p4, p5, p6, p7};
                *(f32x4*)&plds[row * 256 + pg0 * 4] = v0;
                *(f32x4*)&plds[row * 256 + pg1 * 4] = v1;

                union { unsigned u[4]; bf16x8 v; } pa;
                pa.u[0] = cvtpk(p0, p1); pa.u[1] = cvtpk(p2, p3);
                pa.u[2] = cvtpk(p4, p5); pa.u[3] = cvtpk(p6, p7);
#pragma unroll
                for (int nt = 0; nt < 4; nt++) {
                    union { short4 s4[2]; bf16x8 v; } vv;
                    vv.s4[0] = vf.x[2 * nt];
                    vv.s4[1] = vf.x[2 * nt + 1];
                    o[j][nt] = MFMA16(vv.v, pa.v, o[j][nt]);
                }
            }
        }
        __syncthreads();

        // store phase: wave w owns rows 8w..8w+7; 1KB contiguous per instr
#pragma unroll
        for (int rr = 0; rr < 8; rr++) {
            int R = w * 8 + rr;
            float* arow = attn + ((long)(bh * SEQ + q0 + R)) * SEQ + chunk * 256;
            int pg = (lane & ~7) | ((lane & 7) ^ (R & 7));
            f32x4 val = *(const f32x4*)&plds[R * 256 + pg * 4];
            __builtin_nontemporal_store(val, (f32x4*)(arow + lane * 4));
        }
        __syncthreads();
    }

    // ---- O merge across the 4 col-subchunk waves (reuse plds) ----
    if (kc != 0) {
#pragma unroll
        for (int j = 0; j < 2; j++)
#pragma unroll
            for (int nt = 0; nt < 4; nt++)
                *(f32x4*)&plds[((((wq2 * 3 + (kc - 1)) * 2 + j) * 4 + nt) * 64 + lane) * 4] =
                    o[j][nt];
    }
    __syncthreads();
    if (kc == 0) {
        int b = bh / NHEADS, head = bh % NHEADS;
#pragma unroll
        for (int j = 0; j < 2; j++) {
            long crow = ((long)(b * SEQ + qbase + 16 * j + r)) * D_MODEL + head * DEPTH;
#pragma unroll
            for (int nt = 0; nt < 4; nt++) {
                f32x4 acc = o[j][nt];
#pragma unroll
                for (int m = 0; m < 3; m++) {
                    f32x4 op = *(const f32x4*)
                        &plds[((((wq2 * 3 + m) * 2 + j) * 4 + nt) * 64 + lane) * 4];
                    acc[0] += op[0]; acc[1] += op[1];
                    acc[2] += op[2]; acc[3] += op[3];
                }
                *(unsigned*)&ctx[crow + 16 * nt + 4 * h]     = cvtpk(acc[0], acc[1]);
                *(unsigned*)&ctx[crow + 16 * nt + 4 * h + 2] = cvtpk(acc[2], acc[3]);
            }
        }
    }
}

// ---------------------------------------------------------------------------
// Kernel C: output projection; 128-row blocks (8 waves), dbuf, float4 stores.
// ---------------------------------------------------------------------------
__global__ __launch_bounds__(512) void out_gemm(
    const short* __restrict__ ctx, const short* __restrict__ wt3,
    const float* __restrict__ bo, float* __restrict__ out)
{
    int m0 = blockIdx.x * 128, n0 = blockIdx.y * 64;
    int lane = threadIdx.x & 63, w = threadIdx.x >> 6;   // w in 0..7
    int r = lane & 15, h = lane >> 4;

    f32x4 acc[4] = {};
    const short* arow = ctx + (m0 + 16 * w + r) * D_MODEL;

    bf16x8 ac = *(const bf16x8*)(arow + 8 * h);
    bf16x8 bc[4];
#pragma unroll
    for (int nt = 0; nt < 4; nt++)
        bc[nt] = *(const bf16x8*)(wt3 + (n0 + 16 * nt + r) * D_MODEL + 8 * h);

    for (int k0 = 0; k0 < D_MODEL; k0 += 32) {
        int kn = (k0 + 32 < D_MODEL) ? (k0 + 32) : 0;
        bf16x8 an = *(const bf16x8*)(arow + kn + 8 * h);
        bf16x8 bn[4];
#pragma unroll
        for (int nt = 0; nt < 4; nt++)
            bn[nt] = *(const bf16x8*)(wt3 + (n0 + 16 * nt + r) * D_MODEL + kn + 8 * h);
#pragma unroll
        for (int nt = 0; nt < 4; nt++)
            acc[nt] = MFMA16(bc[nt], ac, acc[nt]);   // SWAPPED: rows=n, cols=m
        ac = an;
#pragma unroll
        for (int nt = 0; nt < 4; nt++) bc[nt] = bn[nt];
    }
    int m = m0 + 16 * w + r;
#pragma unroll
    for (int nt = 0; nt < 4; nt++) {
        int n = n0 + 16 * nt + 4 * h;
        float4 b4 = *(const float4*)(bo + n);
        f32x4 res = {acc[nt][0] + b4.x, acc[nt][1] + b4.y,
                     acc[nt][2] + b4.z, acc[nt][3] + b4.w};
        *(f32x4*)(out + (long)m * D_MODEL + n) = res;
    }
}

// ---------------------------------------------------------------------------
extern "C" void kernel_launch(void* const* d_in, const int* in_sizes, int n_in,
                              void* d_out, int out_size, void* d_ws, size_t ws_size,
                              hipStream_t stream)
{
    const float* v  = (const float*)d_in[0];
    const float* k  = (const float*)d_in[1];
    const float* q  = (const float*)d_in[2];
    const float* wq = (const float*)d_in[3];
    const float* bq = (const float*)d_in[4];
    const float* wk = (const float*)d_in[5];
    const float* bk = (const float*)d_in[6];
    const float* wv = (const float*)d_in[7];
    const float* bv = (const float*)d_in[8];
    const float* wo = (const float*)d_in[9];
    const float* bo = (const float*)d_in[10];

    char* ws = (char*)d_ws;
    const size_t WT_BYTES  = (size_t)4 * D_MODEL * D_MODEL * 2;    // 4.7 MB
    const size_t XB_BYTES  = (size_t)3 * NROWS * D_MODEL * 2;      // 18.9 MB
    const size_t HB_BYTES  = (size_t)2 * NHEADS * SEQ * DEPTH * 2; // 6.3 MB
    short* wt  = (short*)(ws);
    short* xb  = (short*)(ws + WT_BYTES);
    short* qh  = (short*)(ws + WT_BYTES + XB_BYTES);
    short* kh  = (short*)(ws + WT_BYTES + XB_BYTES + HB_BYTES);
    short* vt  = (short*)(ws + WT_BYTES + XB_BYTES + 2 * HB_BYTES);
    short* ctx = (short*)(ws + WT_BYTES + XB_BYTES + 3 * HB_BYTES);

    float* out  = (float*)d_out;
    float* attn = (float*)d_out + (size_t)NROWS * D_MODEL;

    xcast_kernel<<<dim3(1536, 3), dim3(256), 0, stream>>>(q, k, v, xb);
    wtrans_kernel<<<dim3(24, 24, 4), dim3(256), 0, stream>>>(wq, wk, wv, wo, wt);
    qkv_gemm<<<dim3(32, 12, 3), dim3(512), 0, stream>>>(xb, wt, bq, bk, bv, qh, kh, vt);
    attn_kernel<<<dim3(768), dim3(512), 0, stream>>>(qh, kh, vt, attn, ctx);
    out_gemm<<<dim3(32, 12), dim3(512), 0, stream>>>(ctx, wt + 3 * D_MODEL * D_MODEL, bo, out);
}

// Round 15
// 267.191 us; speedup vs baseline: 1.4189x; 1.3745x over previous
//
#include <hip/hip_runtime.h>

#define D_MODEL 768
#define NHEADS 12
#define DEPTH 64
#define SEQ 2048
#define NROWS 4096   // B*S
#define KBLKS 24     // D_MODEL/32

typedef float f32x4 __attribute__((ext_vector_type(4)));
typedef short bf16x8 __attribute__((ext_vector_type(8)));
typedef unsigned u32x2 __attribute__((ext_vector_type(2)));
typedef unsigned u32x4 __attribute__((ext_vector_type(4)));

#define MFMA16(a, b, c) __builtin_amdgcn_mfma_f32_16x16x32_bf16((a), (b), (c), 0, 0, 0)

__device__ __forceinline__ short f2bf(float f) {
    union { float f; unsigned u; } v; v.f = f;
    unsigned r = (v.u + 0x7FFFu + ((v.u >> 16) & 1u)) >> 16;
    return (short)r;
}
__device__ __forceinline__ unsigned cvtpk(float a, float b) {
    unsigned r;
    asm("v_cvt_pk_bf16_f32 %0, %1, %2" : "=v"(r) : "v"(a), "v"(b));
    return r;
}

struct KF { bf16x8 a0, a1, b0, b1; };          // 16 VGPR
struct VF { short4 x[8]; };                     // 16 VGPR

__device__ __forceinline__ KF loadK(const short* __restrict__ Kp, int k0, int r, int h) {
    KF f;
    const short* kr0 = Kp + (k0 + r) * DEPTH + 8 * h;
    const short* kr1 = kr0 + 16 * DEPTH;
    f.a0 = *(const bf16x8*)(kr0);
    f.a1 = *(const bf16x8*)(kr0 + 32);
    f.b0 = *(const bf16x8*)(kr1);
    f.b1 = *(const bf16x8*)(kr1 + 32);
    return f;
}
// vt blocked layout: [bh][s>>5][d][32]
__device__ __forceinline__ VF loadV(const short* __restrict__ Vb, int k0, int r, int h) {
    VF f;
    const short* blk = Vb + (k0 >> 5) * (DEPTH * 32) + 4 * h;
#pragma unroll
    for (int nt = 0; nt < 4; nt++) {
        const short* row = blk + (16 * nt + r) * 32;
        f.x[2 * nt]     = *(const short4*)(row);
        f.x[2 * nt + 1] = *(const short4*)(row + 16);
    }
    return f;
}

// ---------------------------------------------------------------------------
// Kernel X: cast q,k,v fp32 -> bf16, writing K-BLOCKED layout:
// xb[((z*24 + k/32)*4096 + m)*32 + (k&31)]  -> GEMM fragment loads coalesce.
// ---------------------------------------------------------------------------
__global__ __launch_bounds__(256) void xcast_kernel(
    const float* __restrict__ q, const float* __restrict__ k, const float* __restrict__ v,
    short* __restrict__ xb)
{
    int z = blockIdx.y;
    const float* src = (z == 0) ? q : (z == 1) ? k : v;
    int i = (blockIdx.x * 256 + threadIdx.x) * 8;
    int m = i / D_MODEL;
    int kk = i - m * D_MODEL;
    float4 f0 = *(const float4*)(src + i);
    float4 f1 = *(const float4*)(src + i + 4);
    u32x4 o;
    o[0] = cvtpk(f0.x, f0.y); o[1] = cvtpk(f0.z, f0.w);
    o[2] = cvtpk(f1.x, f1.y); o[3] = cvtpk(f1.z, f1.w);
    size_t off = ((size_t)(z * KBLKS + (kk >> 5)) * NROWS + m) * 32 + (kk & 31);
    *(u32x4*)(xb + off) = o;
}

// ---------------------------------------------------------------------------
// Kernel W: transpose + convert weights to bf16, K-BLOCKED:
// wt[((wi*24 + k/32)*768 + n)*32 + (k&31)]
// ---------------------------------------------------------------------------
__global__ __launch_bounds__(256) void wtrans_kernel(
    const float* __restrict__ wq, const float* __restrict__ wk,
    const float* __restrict__ wv, const float* __restrict__ wo,
    short* __restrict__ wt)
{
    __shared__ float tile[32][33];
    int wi = blockIdx.z;
    const float* W = (wi == 0) ? wq : (wi == 1) ? wk : (wi == 2) ? wv : wo;
    int k0 = blockIdx.x * 32, n0 = blockIdx.y * 32;
    int t = threadIdx.x;
    int tx = t & 31, ty = t >> 5;
#pragma unroll
    for (int i = 0; i < 4; i++) {
        int kk = ty + i * 8;
        tile[kk][tx] = W[(k0 + kk) * D_MODEL + n0 + tx];
    }
    __syncthreads();
    short* outb = wt + ((size_t)(wi * KBLKS + (k0 >> 5)) * D_MODEL) * 32;
#pragma unroll
    for (int i = 0; i < 4; i++) {
        int nn = ty + i * 8;
        outb[(size_t)(n0 + nn) * 32 + tx] = f2bf(tile[tx][nn]);   // tx = k within block
    }
}

// ---------------------------------------------------------------------------
// Kernel A: fused QKV projection GEMM (r12 geometry: 64x64 tile, 4 waves),
// register double-buffered, K-BLOCKED A/B loads (fully coalesced: each
// fragment-set spans one contiguous 1KB region per wave).
// z=0: Q (pre-scaled), z=1: K (swapped-operand, 8B stores);
// z=2: V (k-blocked transposed vt[bh][s>>5][d][s&31]).
// ---------------------------------------------------------------------------
__global__ __launch_bounds__(256) void qkv_gemm(
    const short* __restrict__ xb, const short* __restrict__ wt,
    const float* __restrict__ bq, const float* __restrict__ bk, const float* __restrict__ bv,
    short* __restrict__ qh, short* __restrict__ kh, short* __restrict__ vt)
{
    int z = blockIdx.z;
    int m0 = blockIdx.x * 64, n0 = blockIdx.y * 64;
    int lane = threadIdx.x & 63, w = threadIdx.x >> 6;
    int r = lane & 15, h = lane >> 4;

    // k-blocked bases; per-kblk strides: A += 4096*32, B += 768*32
    const short* Ap = xb + ((size_t)z * KBLKS * NROWS + (m0 + 16 * w + r)) * 32 + 8 * h;
    const short* Bp = wt + ((size_t)z * KBLKS * D_MODEL) * 32;
    const int ASTEP = NROWS * 32, BSTEP = D_MODEL * 32;

    f32x4 acc[4] = {};
    bf16x8 ac = *(const bf16x8*)(Ap);
    bf16x8 bc[4];
#pragma unroll
    for (int nt = 0; nt < 4; nt++)
        bc[nt] = *(const bf16x8*)(Bp + (n0 + 16 * nt + r) * 32 + 8 * h);

    if (z == 2) {
        for (int kb = 0; kb < KBLKS; kb++) {
            int kn = (kb + 1 < KBLKS) ? kb + 1 : 0;
            bf16x8 an = *(const bf16x8*)(Ap + (size_t)kn * ASTEP);
            bf16x8 bn[4];
#pragma unroll
            for (int nt = 0; nt < 4; nt++)
                bn[nt] = *(const bf16x8*)(Bp + (size_t)kn * BSTEP + (n0 + 16 * nt + r) * 32 + 8 * h);
#pragma unroll
            for (int nt = 0; nt < 4; nt++)
                acc[nt] = MFMA16(ac, bc[nt], acc[nt]);   // rows=s, cols=d
            ac = an;
#pragma unroll
            for (int nt = 0; nt < 4; nt++) bc[nt] = bn[nt];
        }
#pragma unroll
        for (int nt = 0; nt < 4; nt++) {
            int col = n0 + 16 * nt + r;
            float bsv = bv[col];
            int hh = col >> 6, dd = col & 63;
            int m = m0 + 16 * w + 4 * h;
            int b = m >> 11, s = m & 2047;
            short4 pk;
            pk.x = f2bf(acc[nt][0] + bsv);
            pk.y = f2bf(acc[nt][1] + bsv);
            pk.z = f2bf(acc[nt][2] + bsv);
            pk.w = f2bf(acc[nt][3] + bsv);
            long off = (((long)(b * NHEADS + hh) * 64 + (s >> 5)) * DEPTH + dd) * 32 + (s & 31);
            *(short4*)(vt + off) = pk;
        }
    } else {
        const float* bias = (z == 0) ? bq : bk;
        float scl = (z == 0) ? 0.18033688011112042f : 1.0f;  // 0.125*log2(e)
        short* dst = (z == 0) ? qh : kh;
        for (int kb = 0; kb < KBLKS; kb++) {
            int kn = (kb + 1 < KBLKS) ? kb + 1 : 0;
            bf16x8 an = *(const bf16x8*)(Ap + (size_t)kn * ASTEP);
            bf16x8 bn[4];
#pragma unroll
            for (int nt = 0; nt < 4; nt++)
                bn[nt] = *(const bf16x8*)(Bp + (size_t)kn * BSTEP + (n0 + 16 * nt + r) * 32 + 8 * h);
#pragma unroll
            for (int nt = 0; nt < 4; nt++)
                acc[nt] = MFMA16(bc[nt], ac, acc[nt]);   // SWAPPED: rows=d, cols=s
            ac = an;
#pragma unroll
            for (int nt = 0; nt < 4; nt++) bc[nt] = bn[nt];
        }
        int hh = n0 >> 6;
        int m = m0 + 16 * w + r;
        int b = m >> 11, s = m & 2047;
        long rowoff = ((long)(b * NHEADS + hh) * SEQ + s) * DEPTH;
#pragma unroll
        for (int nt = 0; nt < 4; nt++) {
            int dd = 16 * nt + 4 * h;
            float4 b4 = *(const float4*)(bias + n0 + dd);
            float v0 = (acc[nt][0] + b4.x) * scl;
            float v1 = (acc[nt][1] + b4.y) * scl;
            float v2 = (acc[nt][2] + b4.z) * scl;
            float v3 = (acc[nt][3] + b4.w) * scl;
            u32x2 pk = {cvtpk(v0, v1), cvtpk(v2, v3)};
            *(u32x2*)&dst[rowoff + dd] = pk;
        }
    }
}

// ---------------------------------------------------------------------------
// Kernel B: attention v7 — EXACT r12 structure (proven 340 µs). QK once,
// phased NT stores, PV fused, no pass-2 prefetch, __launch_bounds__(512,4).
// ---------------------------------------------------------------------------
__global__ __launch_bounds__(512, 4) void attn_kernel(
    const short* __restrict__ qh, const short* __restrict__ kh, const short* __restrict__ vt,
    float* __restrict__ attn, short* __restrict__ ctx)
{
    __shared__ float plds[64 * 256];          // 64 KB P-chunk / O-merge buffer
    __shared__ float sml[2][4][2][16];

    int wgid = blockIdx.x;
    int xcd = wgid & 7;
    int idx = wgid >> 3;             // 0..95
    int bh = xcd * 3 + (idx >> 5);   // 3 heads per XCD
    int q0 = (idx & 31) * 64;

    int lane = threadIdx.x & 63, w = threadIdx.x >> 6;
    int wq2 = w >> 2, kc = w & 3;    // q-group (32 rows), col-subchunk (64)
    int r = lane & 15, h = lane >> 4;
    int qbase = q0 + 32 * wq2;

    const short* Qp = qh + ((long)bh * SEQ + qbase) * DEPTH;
    const short* Kp = kh + (long)bh * SEQ * DEPTH;
    const short* Vb = vt + (long)bh * (64 * DEPTH * 32);

    bf16x8 qf[2][2];
#pragma unroll
    for (int j = 0; j < 2; j++) {
        qf[j][0] = *(const bf16x8*)(Qp + (16 * j + r) * DEPTH + 8 * h);
        qf[j][1] = *(const bf16x8*)(Qp + (16 * j + r) * DEPTH + 32 + 8 * h);
    }

    // ---- pass 1: K-only sums over this wave's k-quarter ----
    float l0 = 0.f, l1 = 0.f;
    {
        int kstart = kc * 512, kend = kstart + 512;
        KF kcur = loadK(Kp, kstart, r, h);
        for (int k0 = kstart; k0 < kend; k0 += 32) {
            int kn = (k0 + 32 < kend) ? (k0 + 32) : kstart;
            KF knxt = loadK(Kp, kn, r, h);
#pragma unroll
            for (int j = 0; j < 2; j++) {
                f32x4 s0 = {}, s1 = {};
                s0 = MFMA16(kcur.a0, qf[j][0], s0);
                s1 = MFMA16(kcur.b0, qf[j][0], s1);
                s0 = MFMA16(kcur.a1, qf[j][1], s0);
                s1 = MFMA16(kcur.b1, qf[j][1], s1);
                float sum = exp2f(s0[0]) + exp2f(s0[1]) + exp2f(s0[2]) + exp2f(s0[3])
                          + exp2f(s1[0]) + exp2f(s1[1]) + exp2f(s1[2]) + exp2f(s1[3]);
                if (j == 0) l0 += sum; else l1 += sum;
            }
            kcur = knxt;
        }
    }
    l0 += __shfl_xor(l0, 16); l0 += __shfl_xor(l0, 32);
    l1 += __shfl_xor(l1, 16); l1 += __shfl_xor(l1, 32);
    if (lane < 16) {
        sml[wq2][kc][0][lane] = l0;
        sml[wq2][kc][1][lane] = l1;
    }
    __syncthreads();
    float rl[2];
#pragma unroll
    for (int j = 0; j < 2; j++)
        rl[j] = 1.0f / (sml[wq2][0][j][r] + sml[wq2][1][j][r] +
                        sml[wq2][2][j][r] + sml[wq2][3][j][r]);

    // ---- pass 2: chunked compute -> LDS -> phased NT stores; PV fused ----
    f32x4 o[2][4] = {};
    int rsw = r & 7;

    for (int chunk = 0; chunk < 8; chunk++) {
#pragma unroll
        for (int it = 0; it < 2; it++) {
            int k0 = chunk * 256 + kc * 64 + it * 32;
            KF kf = loadK(Kp, k0, r, h);
            VF vf = loadV(Vb, k0, r, h);
#pragma unroll
            for (int j = 0; j < 2; j++) {
                f32x4 s0 = {}, s1 = {};
                s0 = MFMA16(kf.a0, qf[j][0], s0);
                s1 = MFMA16(kf.b0, qf[j][0], s1);
                s0 = MFMA16(kf.a1, qf[j][1], s0);
                s1 = MFMA16(kf.b1, qf[j][1], s1);

                float p0 = exp2f(s0[0]) * rl[j], p1 = exp2f(s0[1]) * rl[j];
                float p2 = exp2f(s0[2]) * rl[j], p3 = exp2f(s0[3]) * rl[j];
                float p4 = exp2f(s1[0]) * rl[j], p5 = exp2f(s1[1]) * rl[j];
                float p6 = exp2f(s1[2]) * rl[j], p7 = exp2f(s1[3]) * rl[j];

                int row = wq2 * 32 + 16 * j + r;
                int G0 = kc * 16 + it * 8 + h;
                int G1 = G0 + 4;
                int pg0 = (G0 & ~7) | ((G0 & 7) ^ rsw);
                int pg1 = (G1 & ~7) | ((G1 & 7) ^ rsw);
                f32x4 v0 = {p0, p1, p2, p3};
                f32x4 v1 = {p4, p5, p6, p7};
                *(f32x4*)&plds[row * 256 + pg0 * 4] = v0;
                *(f32x4*)&plds[row * 256 + pg1 * 4] = v1;

                union { unsigned u[4]; bf16x8 v; } pa;
                pa.u[0] = cvtpk(p0, p1); pa.u[1] = cvtpk(p2, p3);
                pa.u[2] = cvtpk(p4, p5); pa.u[3] = cvtpk(p6, p7);
#pragma unroll
                for (int nt = 0; nt < 4; nt++) {
                    union { short4 s4[2]; bf16x8 v; } vv;
                    vv.s4[0] = vf.x[2 * nt];
                    vv.s4[1] = vf.x[2 * nt + 1];
                    o[j][nt] = MFMA16(vv.v, pa.v, o[j][nt]);
                }
            }
        }
        __syncthreads();

        // store phase: wave w owns rows 8w..8w+7; 1KB contiguous per instr
#pragma unroll
        for (int rr = 0; rr < 8; rr++) {
            int R = w * 8 + rr;
            float* arow = attn + ((long)(bh * SEQ + q0 + R)) * SEQ + chunk * 256;
            int pg = (lane & ~7) | ((lane & 7) ^ (R & 7));
            f32x4 val = *(const f32x4*)&plds[R * 256 + pg * 4];
            __builtin_nontemporal_store(val, (f32x4*)(arow + lane * 4));
        }
        __syncthreads();
    }

    // ---- O merge across the 4 col-subchunk waves (reuse plds) ----
    if (kc != 0) {
#pragma unroll
        for (int j = 0; j < 2; j++)
#pragma unroll
            for (int nt = 0; nt < 4; nt++)
                *(f32x4*)&plds[((((wq2 * 3 + (kc - 1)) * 2 + j) * 4 + nt) * 64 + lane) * 4] =
                    o[j][nt];
    }
    __syncthreads();
    if (kc == 0) {
        int b = bh / NHEADS, head = bh % NHEADS;
#pragma unroll
        for (int j = 0; j < 2; j++) {
            long crow = ((long)(b * SEQ + qbase + 16 * j + r)) * D_MODEL + head * DEPTH;
#pragma unroll
            for (int nt = 0; nt < 4; nt++) {
                f32x4 acc = o[j][nt];
#pragma unroll
                for (int m = 0; m < 3; m++) {
                    f32x4 op = *(const f32x4*)
                        &plds[((((wq2 * 3 + m) * 2 + j) * 4 + nt) * 64 + lane) * 4];
                    acc[0] += op[0]; acc[1] += op[1];
                    acc[2] += op[2]; acc[3] += op[3];
                }
                *(unsigned*)&ctx[crow + 16 * nt + 4 * h]     = cvtpk(acc[0], acc[1]);
                *(unsigned*)&ctx[crow + 16 * nt + 4 * h + 2] = cvtpk(acc[2], acc[3]);
            }
        }
    }
}

// ---------------------------------------------------------------------------
// Kernel C: output projection (r12 geometry: 64x64, 4 waves), dbuf;
// B loads K-BLOCKED (coalesced), A (ctx) row-major; float4 stores.
// ---------------------------------------------------------------------------
__global__ __launch_bounds__(256) void out_gemm(
    const short* __restrict__ ctx, const short* __restrict__ wt,
    const float* __restrict__ bo, float* __restrict__ out)
{
    int m0 = blockIdx.x * 64, n0 = blockIdx.y * 64;
    int lane = threadIdx.x & 63, w = threadIdx.x >> 6;
    int r = lane & 15, h = lane >> 4;

    f32x4 acc[4] = {};
    const short* arow = ctx + (m0 + 16 * w + r) * D_MODEL;
    const short* Bp = wt + ((size_t)3 * KBLKS * D_MODEL) * 32;   // wo, k-blocked
    const int BSTEP = D_MODEL * 32;

    bf16x8 ac = *(const bf16x8*)(arow + 8 * h);
    bf16x8 bc[4];
#pragma unroll
    for (int nt = 0; nt < 4; nt++)
        bc[nt] = *(const bf16x8*)(Bp + (n0 + 16 * nt + r) * 32 + 8 * h);

    for (int kb = 0; kb < KBLKS; kb++) {
        int kn = (kb + 1 < KBLKS) ? kb + 1 : 0;
        bf16x8 an = *(const bf16x8*)(arow + kn * 32 + 8 * h);
        bf16x8 bn[4];
#pragma unroll
        for (int nt = 0; nt < 4; nt++)
            bn[nt] = *(const bf16x8*)(Bp + (size_t)kn * BSTEP + (n0 + 16 * nt + r) * 32 + 8 * h);
#pragma unroll
        for (int nt = 0; nt < 4; nt++)
            acc[nt] = MFMA16(bc[nt], ac, acc[nt]);   // SWAPPED: rows=n, cols=m
        ac = an;
#pragma unroll
        for (int nt = 0; nt < 4; nt++) bc[nt] = bn[nt];
    }
    int m = m0 + 16 * w + r;
#pragma unroll
    for (int nt = 0; nt < 4; nt++) {
        int n = n0 + 16 * nt + 4 * h;
        float4 b4 = *(const float4*)(bo + n);
        f32x4 res = {acc[nt][0] + b4.x, acc[nt][1] + b4.y,
                     acc[nt][2] + b4.z, acc[nt][3] + b4.w};
        *(f32x4*)(out + (long)m * D_MODEL + n) = res;
    }
}

// ---------------------------------------------------------------------------
extern "C" void kernel_launch(void* const* d_in, const int* in_sizes, int n_in,
                              void* d_out, int out_size, void* d_ws, size_t ws_size,
                              hipStream_t stream)
{
    const float* v  = (const float*)d_in[0];
    const float* k  = (const float*)d_in[1];
    const float* q  = (const float*)d_in[2];
    const float* wq = (const float*)d_in[3];
    const float* bq = (const float*)d_in[4];
    const float* wk = (const float*)d_in[5];
    const float* bk = (const float*)d_in[6];
    const float* wv = (const float*)d_in[7];
    const float* bv = (const float*)d_in[8];
    const float* wo = (const float*)d_in[9];
    const float* bo = (const float*)d_in[10];

    char* ws = (char*)d_ws;
    const size_t WT_BYTES  = (size_t)4 * D_MODEL * D_MODEL * 2;    // 4.7 MB
    const size_t XB_BYTES  = (size_t)3 * NROWS * D_MODEL * 2;      // 18.9 MB
    const size_t HB_BYTES  = (size_t)2 * NHEADS * SEQ * DEPTH * 2; // 6.3 MB
    short* wt  = (short*)(ws);
    short* xb  = (short*)(ws + WT_BYTES);
    short* qh  = (short*)(ws + WT_BYTES + XB_BYTES);
    short* kh  = (short*)(ws + WT_BYTES + XB_BYTES + HB_BYTES);
    short* vt  = (short*)(ws + WT_BYTES + XB_BYTES + 2 * HB_BYTES);
    short* ctx = (short*)(ws + WT_BYTES + XB_BYTES + 3 * HB_BYTES);

    float* out  = (float*)d_out;
    float* attn = (float*)d_out + (size_t)NROWS * D_MODEL;

    xcast_kernel<<<dim3(1536, 3), dim3(256), 0, stream>>>(q, k, v, xb);
    wtrans_kernel<<<dim3(24, 24, 4), dim3(256), 0, stream>>>(wq, wk, wv, wo, wt);
    qkv_gemm<<<dim3(64, 12, 3), dim3(256), 0, stream>>>(xb, wt, bq, bk, bv, qh, kh, vt);
    attn_kernel<<<dim3(768), dim3(512), 0, stream>>>(qh, kh, vt, attn, ctx);
    out_gemm<<<dim3(64, 12), dim3(256), 0, stream>>>(ctx, wt, bo, out);
}